// Round 1
// 776.245 us; speedup vs baseline: 1.0471x; 1.0471x over previous
//
#include <hip/hip_runtime.h>
#include <stdint.h>

// Problem constants
#define MROWS 32768      // B*S = 8*4096
#define KD    256        // 2*DIM
#define VOCABN 8192

typedef _Float16 half8  __attribute__((ext_vector_type(8)));
typedef _Float16 half4v __attribute__((ext_vector_type(4)));
typedef float  floatx4  __attribute__((ext_vector_type(4)));

// scratch layout (byte offsets within d_ws; ws_size >= WS_NEED verified R3/R4)
#define A_OFF     0u          // f16 z  [32768][256]  = 16,777,216 B
#define B_OFF     16777216u   // f16 cb [8192][256]   =  4,194,304 B
#define CN_OFF    20971520u   // f32 0.5*||c||^2 [8192] = 32,768 B
#define PART_OFF  21004288u   // float4 top2 [32768][8] = 4,194,304 B
#define IDX_OFF   25198592u   // int idx [32768] = 131,072 B
#define WS_NEED   25329664u

// ---- top-2 (max sigma) with smaller-index tie-break (flush/merge path) ----
struct Top2 { float s1; int i1; float s2; int i2; };

__device__ __forceinline__ bool better(float sa, int ia, float sb, int ib) {
    return (sa > sb) || (sa == sb && ia < ib);
}
__device__ __forceinline__ Top2 merge2(const Top2& a, const Top2& b) {
    Top2 r;
    if (better(b.s1, b.i1, a.s1, a.i1)) {
        r.s1 = b.s1; r.i1 = b.i1;
        if (better(a.s1, a.i1, b.s2, b.i2)) { r.s2 = a.s1; r.i2 = a.i1; }
        else                                { r.s2 = b.s2; r.i2 = b.i2; }
    } else {
        r.s1 = a.s1; r.i1 = a.i1;
        if (better(b.s1, b.i1, a.s2, a.i2)) { r.s2 = b.s1; r.i2 = b.i1; }
        else                                { r.s2 = a.s2; r.i2 = a.i2; }
    }
    return r;
}

// async global->LDS, 16 B per lane. LDS dest is WAVE-UNIFORM base + lane*16;
// global src is per-lane (this is how the swizzle is applied: pre-permuted src).
__device__ __forceinline__ void gll16(const _Float16* g, const char* l) {
    __builtin_amdgcn_global_load_lds(
        (const __attribute__((address_space(1))) void*)g,
        (__attribute__((address_space(3))) void*)l, 16, 0, 0);
}

// ---- 1. z = concat(real,imag) as f16 [32768][256] ----
__global__ __launch_bounds__(256) void prep_z(const float* __restrict__ gr,
                                              const float* __restrict__ gi,
                                              _Float16* __restrict__ A) {
    int t = blockIdx.x * 256 + threadIdx.x;     // 4 elements/thread
    int base = t * 4;
    int m = base >> 8;
    int k = base & 255;
    float4 v;
    if (k < 128) v = *(const float4*)(gr + (size_t)m * 128 + k);
    else         v = *(const float4*)(gi + (size_t)m * 128 + (k - 128));
    half4v h;
    h[0] = (_Float16)v.x; h[1] = (_Float16)v.y;
    h[2] = (_Float16)v.z; h[3] = (_Float16)v.w;
    *(half4v*)(A + base) = h;
}

// ---- 2. codebook f16 [8192][256] + 0.5*||c||^2 fp32 ----
__global__ __launch_bounds__(64) void prep_c(const float* __restrict__ cb,
                                             _Float16* __restrict__ B,
                                             float* __restrict__ cnorm) {
    int v = blockIdx.x;
    int lane = threadIdx.x;                    // 0..63, 4 floats each
    float4 c = ((const float4*)(cb + (size_t)v * 256))[lane];
    half4v h;
    h[0] = (_Float16)c.x; h[1] = (_Float16)c.y;
    h[2] = (_Float16)c.z; h[3] = (_Float16)c.w;
    ((half4v*)(B + (size_t)v * 256))[lane] = h;
    float s = c.x * c.x + c.y * c.y + c.z * c.z + c.w * c.w;
    #pragma unroll
    for (int m = 32; m; m >>= 1) s += __shfl_xor(s, m);
    if (lane == 0) cnorm[v] = 0.5f * s;
}

// ---- 3. f16 GEMM + per-row top-2 argmax(sigma), LDS-staged B (R15) ----
// R14/R15 post-mortem: the no-LDS register pipeline (590 us) stalled ~67% of
// the time: af(64)+buf(64)+acc(32)+t2(32) regs oversubscribe the file, so the
// compiler serializes the 8-load "prefetch" (measured ~600cy/load exposed).
// Fix = m97 structure: global_load_lds (NO VGPR dests) double-buffered 32-KB
// half-K slices, stage-next issued BEFORE compute-current, ONE barrier/slice;
// the vmcnt drain hides under ~1240cy of MFMA per CU-slice. ds_read would be a
// 16-way bank conflict (256-B rows) -> T2 chunk-XOR swizzle, applied as
// linear LDS dest + pre-permuted GLOBAL src + XOR'd ds_read addr (both-sides
// rule). topbuf aliases buf1's first 2 KB (dead at every flush): LDS = 64 KB
// exactly -> 2 blocks/CU. Streaming top-2 update cut ~14 -> ~7 VALU/elem:
// -0.5||c||^2 folded into acc init; max/med3 scores; tie-break deferred to
// resolve's fp64 refine (flush/merge keeps full better()).
__global__ __launch_bounds__(256) void gemm_argmin(const _Float16* __restrict__ A,
                                                   const _Float16* __restrict__ B,
                                                   const float* __restrict__ cnorm,
                                                   float4* __restrict__ part) {
    // 64 KB LDS: two 32-KB slice buffers [col 128][k 128] f16 (256 B rows).
    __shared__ __align__(16) char lds[65536];
    _Float16* buf0 = (_Float16*)lds;
    _Float16* buf1 = (_Float16*)(lds + 32768);
    float4*  topbuf = (float4*)(lds + 32768);   // aliases buf1 (dead at flush)

    const int tid = threadIdx.x;
    const int m0 = blockIdx.x * 64;
    const int wave = tid >> 6, lane = tid & 63;
    const int wr = wave >> 1, wc = wave & 1;           // 2x2: 32 rows x 64 cols
    const int lane16 = lane & 15, quad = lane >> 4;

    // A-fragments direct from global (once): row m0+wr*32+i*16+lane16,
    // k = s*64 + ks*32 + quad*8  (AGPR-resident for the whole kernel)
    half8 af[2][4][2];   // [i][s][ks]
    #pragma unroll
    for (int i = 0; i < 2; ++i) {
        const _Float16* ar = A + (size_t)(m0 + wr * 32 + i * 16 + lane16) * 256
                               + quad * 8;
        #pragma unroll
        for (int s = 0; s < 4; ++s)
            #pragma unroll
            for (int ks = 0; ks < 2; ++ks)
                af[i][s][ks] = *(const half8*)(ar + s * 64 + ks * 32);
    }

    // ---- staging geometry ----
    // slice u = g*2+h holds B rows [g*128,g*128+128), k in [h*128,h*128+128).
    // Wave w stages cols [w*32, w*32+32) = 8 wave-loads of 1 KB (4 cols each).
    // Lane L lands at LDS col = colbase + (L>>4), physChunk = L&15; it must
    // FETCH logical chunk (L&15) ^ (col&7) so the XOR'd reader sees B[col][k].
    const int st_col = lane >> 4;          // 0..3 col within a wave-load
    const int st_pch = lane & 15;          // physical 16-B chunk slot
    const _Float16* gsrc[8];               // per-lane source, + g*32768 + h*128
    uint32_t lbase[8];                     // wave-uniform LDS byte base
    #pragma unroll
    for (int q = 0; q < 8; ++q) {
        int colb = wave * 32 + q * 4;                  // uniform
        int col  = colb + st_col;                      // 0..127 per-lane
        int logc = st_pch ^ (col & 7);                 // inverse swizzle
        gsrc[q]  = B + (size_t)col * 256 + logc * 8;   // f16 units
        lbase[q] = (uint32_t)colb * 256;               // bytes
    }

    // fragment ds_read offsets (bytes within a buffer):
    // off(j,sub,ks) = (wc*64+j*16+lane16)*256 + sub*128
    //               + ((ks*4+quad) ^ (lane16&7))*16     [the read-side XOR]
    const uint32_t fr_base = (uint32_t)(wc * 64 + lane16) * 256;
    uint32_t cq[2];
    #pragma unroll
    for (int ks = 0; ks < 2; ++ks)
        cq[ks] = (uint32_t)(((ks * 4 + quad) ^ (lane16 & 7)) * 16);

    Top2 t2[2][4];
    #pragma unroll
    for (int i = 0; i < 2; ++i)
        #pragma unroll
        for (int r = 0; r < 4; ++r)
            t2[i][r] = Top2{-3.4e38f, 0x7fffffff, -3.4e38f, 0x7fffffff};

    // prologue: stage slice 0 (g=0,h=0) -> buf0
    #pragma unroll
    for (int q = 0; q < 8; ++q)
        gll16(gsrc[q], (const char*)buf0 + lbase[q]);
    __syncthreads();

    for (int g = 0; g < 64; ++g) {
        const int n0 = g * 128;

        // acc init = -0.5*||c||^2 (folds the score bias into the MFMA C-in)
        floatx4 acc[2][4];
        #pragma unroll
        for (int j = 0; j < 4; ++j) {
            float nh = -cnorm[n0 + wc * 64 + j * 16 + lane16];
            acc[0][j] = (floatx4){nh, nh, nh, nh};
            acc[1][j] = acc[0][j];
        }

        #pragma unroll
        for (int h = 0; h < 2; ++h) {
            _Float16* cur = h ? buf1 : buf0;
            // stage next slice into the other buffer (in flight over MFMAs)
            if (h == 0) {                          // next = (g, h=1) -> buf1
                const size_t goff = (size_t)g * 32768 + 128;
                #pragma unroll
                for (int q = 0; q < 8; ++q)
                    gll16(gsrc[q] + goff, (const char*)buf1 + lbase[q]);
            } else if (g < 63) {                   // next = (g+1, 0) -> buf0
                const size_t goff = (size_t)(g + 1) * 32768;
                #pragma unroll
                for (int q = 0; q < 8; ++q)
                    gll16(gsrc[q] + goff, (const char*)buf0 + lbase[q]);
            }
            // compute current slice: 16 ds_read_b128 + 32 MFMA
            #pragma unroll
            for (int sub = 0; sub < 2; ++sub) {
                half8 bf[4][2];
                #pragma unroll
                for (int j = 0; j < 4; ++j)
                    #pragma unroll
                    for (int ks = 0; ks < 2; ++ks)
                        bf[j][ks] = *(const half8*)((const char*)cur + fr_base
                                                    + j * 4096 + sub * 128 + cq[ks]);
                #pragma unroll
                for (int ks = 0; ks < 2; ++ks)
                    #pragma unroll
                    for (int i = 0; i < 2; ++i)
                        #pragma unroll
                        for (int j = 0; j < 4; ++j)
                            acc[i][j] = __builtin_amdgcn_mfma_f32_16x16x32_f16(
                                af[i][h * 2 + sub][ks], bf[j][ks],
                                acc[i][j], 0, 0, 0);
            }
            // drains this slice's stage loads (vmcnt) + publishes the buffer
            __syncthreads();
        }

        // per-g top-2 update (registers; C/D: col=lane&15, row=quad*4+reg).
        // Cheap form: max + med3 + 2 cmp + 3 cndmask; no in-loop index
        // tie-break (exact ties land both in top-2 or trigger fp64 refine).
        const int colb = n0 + wc * 64 + lane16;
        #pragma unroll
        for (int i = 0; i < 2; ++i)
            #pragma unroll
            for (int r = 0; r < 4; ++r) {
                Top2& t = t2[i][r];
                #pragma unroll
                for (int j = 0; j < 4; ++j) {
                    float sv = acc[i][j][r];
                    int col = colb + j * 16;
                    bool gt1 = sv > t.s1;
                    bool gt2 = sv > t.s2;
#if __has_builtin(__builtin_amdgcn_fmed3f)
                    float ns2 = __builtin_amdgcn_fmed3f(sv, t.s2, t.s1);
#else
                    float ns2 = gt1 ? t.s1 : (gt2 ? sv : t.s2);
#endif
                    t.i2 = gt1 ? t.i1 : (gt2 ? col : t.i2);
                    t.i1 = gt1 ? col : t.i1;
                    t.s1 = gt1 ? sv  : t.s1;
                    t.s2 = ns2;
                }
            }

        // flush every 8 g: butterfly + cross-wave merge + part write.
        // topbuf aliases buf1: buf1's slice was consumed before the h=1
        // barrier, and the next write to buf1 (stage of slice 2g+3) is only
        // issued after the flush's closing barrier -> no hazard.
        if ((g & 7) == 7) {
            const int slot = g >> 3;
            #pragma unroll
            for (int i = 0; i < 2; ++i)
                #pragma unroll
                for (int r = 0; r < 4; ++r) {
                    Top2 t = t2[i][r];
                    #pragma unroll
                    for (int m = 1; m < 16; m <<= 1) {
                        Top2 o;
                        o.s1 = __shfl_xor(t.s1, m); o.i1 = __shfl_xor(t.i1, m);
                        o.s2 = __shfl_xor(t.s2, m); o.i2 = __shfl_xor(t.i2, m);
                        t = merge2(t, o);
                    }
                    if (lane16 == 0) {
                        int rl = wr * 32 + i * 16 + quad * 4 + r;   // 0..63
                        topbuf[rl * 2 + wc] =
                            make_float4(t.s1, __int_as_float(t.i1),
                                        t.s2, __int_as_float(t.i2));
                    }
                    t2[i][r] = Top2{-3.4e38f, 0x7fffffff, -3.4e38f, 0x7fffffff};
                }
            __syncthreads();
            if (tid < 64) {
                float4 e0 = topbuf[tid * 2 + 0], e1 = topbuf[tid * 2 + 1];
                Top2 a{e0.x, __float_as_int(e0.y), e0.z, __float_as_int(e0.w)};
                Top2 b{e1.x, __float_as_int(e1.y), e1.z, __float_as_int(e1.w)};
                Top2 t = merge2(a, b);
                part[(size_t)(m0 + tid) * 8 + slot] =
                    make_float4(t.s1, __int_as_float(t.i1),
                                t.s2, __int_as_float(t.i2));
            }
            __syncthreads();   // topbuf (buf1 alias) reusable next stage
        }
    }
}

// ---- 4. resolve: merge 8 partials/row, fp64-refine near-ties (R4-proven) ----
__global__ __launch_bounds__(256) void resolve(const float4* __restrict__ part,
                                               const float* __restrict__ gr,
                                               const float* __restrict__ gi,
                                               const float* __restrict__ cb,
                                               int* __restrict__ idx) {
    const int row = blockIdx.x * 256 + threadIdx.x;   // grid 128
    float4 e[8];
    #pragma unroll
    for (int j = 0; j < 8; ++j) e[j] = part[(size_t)row * 8 + j];
    Top2 t{-3.4e38f, 0x7fffffff, -3.4e38f, 0x7fffffff};
    #pragma unroll
    for (int j = 0; j < 8; ++j) {
        Top2 o{e[j].x, __float_as_int(e[j].y), e[j].z, __float_as_int(e[j].w)};
        t = merge2(t, o);
    }
    int best = t.i1;
    const float MARGIN = 0.12f;   // ~7.7 sigma of f16-screen score-diff noise
    if (t.s1 - t.s2 < MARGIN) {
        double bd = 1e300; int bi = 0x7fffffff;
        float cut = t.s1 - MARGIN;
        const float* zr = gr + (size_t)row * 128;
        const float* zi = gi + (size_t)row * 128;
        #pragma unroll
        for (int j = 0; j < 8; ++j) {
            #pragma unroll
            for (int c = 0; c < 2; ++c) {
                float sv = c ? e[j].z : e[j].x;
                int   ci = __float_as_int(c ? e[j].w : e[j].y);
                if (sv >= cut && (unsigned)ci < 8192u) {   // clamp: no wild reads
                    const float* crow = cb + (size_t)ci * 256;
                    double d = 0.0;
                    for (int k = 0; k < 128; ++k) {
                        double a = (double)zr[k] - (double)crow[k];
                        double b = (double)zi[k] - (double)crow[128 + k];
                        d += a * a + b * b;
                    }
                    if (d < bd || (d == bd && ci < bi)) { bd = d; bi = ci; }
                }
            }
        }
        if ((unsigned)bi < 8192u) best = bi;
    }
    idx[row] = ((unsigned)best < 8192u) ? best : 0;
}

// ---- 5a. zero the vq accumulator ----
__global__ void zero_vq(float* __restrict__ out, size_t vq_off) {
    out[vq_off] = 0.f;
}

// ---- 5b. gather + proposal(REAL part only) + salience + vq (one wave/row) ----
__global__ __launch_bounds__(256) void gather_epi(const int* __restrict__ idx,
                                                  const float* __restrict__ gr,
                                                  const float* __restrict__ gi,
                                                  const float* __restrict__ cb,
                                                  const float* __restrict__ salw,
                                                  const float* __restrict__ salb,
                                                  float* __restrict__ out,
                                                  size_t sal_off, size_t vq_off) {
    const int wave = threadIdx.x >> 6, lane = threadIdx.x & 63;
    const int row = blockIdx.x * 4 + wave;
    int id = idx[row];
    if ((unsigned)id >= 8192u) id = 0;   // clamp: no wild reads

    float4 c4 = ((const float4*)(cb + (size_t)id * 256))[lane];
    float4 z4 = (lane < 32) ? ((const float4*)(gr + (size_t)row * 128))[lane]
                            : ((const float4*)(gi + (size_t)row * 128))[lane - 32];

    float dx = c4.x - z4.x, dy = c4.y - z4.y, dz = c4.z - z4.z, dw = c4.w - z4.w;
    float vq = dx * dx + dy * dy + dz * dz + dw * dw;
    float4 w4 = ((const float4*)salw)[lane];
    float sal = c4.x * w4.x + c4.y * w4.y + c4.z * w4.z + c4.w * w4.w;
    #pragma unroll
    for (int m = 1; m < 64; m <<= 1) {
        vq  += __shfl_xor(vq, m);
        sal += __shfl_xor(sal, m);
    }

    // proposal: real part only — lanes 0..31 hold c[0..128) as float4s
    if (lane < 32 && (size_t)(row + 1) * 128 <= sal_off) {
        float4* op = (float4*)(out + (size_t)row * 128);
        op[lane] = c4;
    }
    if (lane == 0 && sal_off + row < vq_off)
        out[sal_off + row] = sal + salb[0];

    __shared__ float vqs[4];
    if (lane == 0) vqs[wave] = vq;
    __syncthreads();
    if (threadIdx.x == 0) {
        float p = (vqs[0] + vqs[1] + vqs[2] + vqs[3]) * (1.25f / 8388608.f);
        atomicAdd(out + vq_off, p);
    }
}

extern "C" void kernel_launch(void* const* d_in, const int* in_sizes, int n_in,
                              void* d_out, int out_size, void* d_ws, size_t ws_size,
                              hipStream_t stream) {
    const float* gr = (const float*)d_in[0];   // gw_real  [8,4096,128]
    const float* gi = (const float*)d_in[1];   // gw_imag  [8,4096,128]
    const float* cb = (const float*)d_in[2];   // codebook [8192,256]
    const float* sw = (const float*)d_in[3];   // sal_w    [1,256]
    const float* sb = (const float*)d_in[4];   // sal_b    [1]
    float* out = (float*)d_out;

    // Output offsets (out_size = 4,227,073 floats:
    // proposal-real 4,194,304 | salience 32,768 | vq_loss 1).
    size_t vq_off  = (size_t)out_size - 1;
    size_t sal_off = (size_t)out_size - 1 - 32768;

    char* base = (char*)d_ws;
    int*  idxb = (int*)(base + IDX_OFF);
    _Float16* A    = (_Float16*)(base + A_OFF);
    _Float16* Bq   = (_Float16*)(base + B_OFF);
    float*    cn   = (float*)   (base + CN_OFF);
    float4*   part = (float4*)  (base + PART_OFF);

    prep_z<<<8192, 256, 0, stream>>>(gr, gi, A);
    prep_c<<<8192, 64, 0, stream>>>(cb, Bq, cn);
    gemm_argmin<<<512, 256, 0, stream>>>(A, Bq, cn, part);
    resolve<<<128, 256, 0, stream>>>(part, gr, gi, cb, idxb);
    zero_vq<<<1, 1, 0, stream>>>(out, vq_off);
    gather_epi<<<8192, 256, 0, stream>>>(idxb, gr, gi, cb, sw, sb, out,
                                         sal_off, vq_off);
}

// Round 2
// 527.510 us; speedup vs baseline: 1.5408x; 1.4715x over previous
//
#include <hip/hip_runtime.h>
#include <stdint.h>

// Problem constants
#define MROWS 32768      // B*S = 8*4096
#define KD    256        // 2*DIM
#define VOCABN 8192

typedef _Float16 half8  __attribute__((ext_vector_type(8)));
typedef _Float16 half4v __attribute__((ext_vector_type(4)));
typedef float  floatx4  __attribute__((ext_vector_type(4)));

// scratch layout (byte offsets within d_ws; ws_size >= WS_NEED verified R3/R4)
#define A_OFF     0u          // f16 z  [32768][256]  = 16,777,216 B
#define B_OFF     16777216u   // f16 cb [8192][256]   =  4,194,304 B
#define CN_OFF    20971520u   // f32 0.5*||c||^2 [8192] = 32,768 B
#define PART_OFF  21004288u   // float4 top2 [32768][8] = 4,194,304 B
#define IDX_OFF   25198592u   // int idx [32768] = 131,072 B
#define WS_NEED   25329664u

// ---- top-2 (max sigma) with smaller-index tie-break (flush/merge path) ----
struct Top2 { float s1; int i1; float s2; int i2; };

__device__ __forceinline__ bool better(float sa, int ia, float sb, int ib) {
    return (sa > sb) || (sa == sb && ia < ib);
}
__device__ __forceinline__ Top2 merge2(const Top2& a, const Top2& b) {
    Top2 r;
    if (better(b.s1, b.i1, a.s1, a.i1)) {
        r.s1 = b.s1; r.i1 = b.i1;
        if (better(a.s1, a.i1, b.s2, b.i2)) { r.s2 = a.s1; r.i2 = a.i1; }
        else                                { r.s2 = b.s2; r.i2 = b.i2; }
    } else {
        r.s1 = a.s1; r.i1 = a.i1;
        if (better(b.s1, b.i1, a.s2, a.i2)) { r.s2 = b.s1; r.i2 = b.i1; }
        else                                { r.s2 = a.s2; r.i2 = a.i2; }
    }
    return r;
}

// async global->LDS, 16 B per lane. LDS dest is WAVE-UNIFORM base + lane*16;
// global src is per-lane (this is how the swizzle is applied: pre-permuted src).
__device__ __forceinline__ void gll16(const void* g, const void* l) {
    __builtin_amdgcn_global_load_lds(
        (const __attribute__((address_space(1))) void*)g,
        (__attribute__((address_space(3))) void*)l, 16, 0, 0);
}

// counted-vmcnt pipe barrier: drains down to N outstanding VMEM ops, then
// raw s_barrier. NEVER vmcnt(0) in the main loop (T3/T4) -- __syncthreads()
// would drain the whole global_load_lds queue (the m97 ~20% stall, which at
// 1-2 blocks/CU is fatal). sched_barrier(0) pins reordering (rule #18).
#define PIPE_SYNC(N) do {                                        \
    asm volatile("s_waitcnt vmcnt(" #N ")" ::: "memory");        \
    __builtin_amdgcn_s_barrier();                                \
    __builtin_amdgcn_sched_barrier(0);                           \
} while (0)

// ---- 1. z = concat(real,imag) as f16 [32768][256] ----
__global__ __launch_bounds__(256) void prep_z(const float* __restrict__ gr,
                                              const float* __restrict__ gi,
                                              _Float16* __restrict__ A) {
    int t = blockIdx.x * 256 + threadIdx.x;     // 4 elements/thread
    int base = t * 4;
    int m = base >> 8;
    int k = base & 255;
    float4 v;
    if (k < 128) v = *(const float4*)(gr + (size_t)m * 128 + k);
    else         v = *(const float4*)(gi + (size_t)m * 128 + (k - 128));
    half4v h;
    h[0] = (_Float16)v.x; h[1] = (_Float16)v.y;
    h[2] = (_Float16)v.z; h[3] = (_Float16)v.w;
    *(half4v*)(A + base) = h;
}

// ---- 2. codebook f16 [8192][256] + 0.5*||c||^2 fp32 ----
__global__ __launch_bounds__(64) void prep_c(const float* __restrict__ cb,
                                             _Float16* __restrict__ B,
                                             float* __restrict__ cnorm) {
    int v = blockIdx.x;
    int lane = threadIdx.x;                    // 0..63, 4 floats each
    float4 c = ((const float4*)(cb + (size_t)v * 256))[lane];
    half4v h;
    h[0] = (_Float16)c.x; h[1] = (_Float16)c.y;
    h[2] = (_Float16)c.z; h[3] = (_Float16)c.w;
    ((half4v*)(B + (size_t)v * 256))[lane] = h;
    float s = c.x * c.x + c.y * c.y + c.z * c.z + c.w * c.w;
    #pragma unroll
    for (int m = 32; m; m >>= 1) s += __shfl_xor(s, m);
    if (lane == 0) cnorm[v] = 0.5f * s;
}

// ---- 3. f16 GEMM + per-row top-2 argmax(sigma), counted-vmcnt pipeline ----
// R15 post-mortem: 64-KB LDS dropped residency to 1 block/CU AND the
// __syncthreads() vmcnt(0)-drain exposed full load latency every slice:
// 10 kcy/g per block (2.2x better than R14's 22) but 2 rounds -> 534 us.
// R16 = T3+T4: slice = 128 cols x 64 k (16 KB), FOUR buffers (buf = v&3,
// compile-time under h-unroll), depth-3 prefetch: issue L(u+3), then
// s_waitcnt vmcnt(8) + raw s_barrier -- only L(u+1) drains; two 16-KB
// batches stay in flight ACROSS the barrier. LDS 68 KB -> 2 blocks/CU.
// cnorm moved into the same DMA pipe (wave0 stages 1 KB/g; acc-init reads
// LDS via lgkm) because per-g VGPR cnorm loads would force in-order vmcnt
// drains. Flushes use lgkmcnt(0)+raw-barrier (no vmcnt drain).
// Floor: max(MFMA 57 us, L2 staging 512x4MB @34.5TB/s = 62 us).
__global__ __launch_bounds__(256) void gemm_argmin(const _Float16* __restrict__ A,
                                                   const _Float16* __restrict__ B,
                                                   const float* __restrict__ cnorm,
                                                   float4* __restrict__ part) {
    // LDS: 4 x 16 KB slice buffers | 2 x 1 KB cnorm | 2 KB topbuf = 68 KB
    __shared__ __align__(16) char lds[69632];
    float4* topbuf = (float4*)(lds + 67584);

    const int tid = threadIdx.x;
    const int m0 = blockIdx.x * 64;
    const int wave = tid >> 6, lane = tid & 63;
    const int wr = wave >> 1, wc = wave & 1;           // 2x2: 32 rows x 64 cols
    const int lane16 = lane & 15, quad = lane >> 4;

    // A-fragments direct from global (once): row m0+wr*32+i*16+lane16,
    // k = s*64 + ks*32 + quad*8  (register-resident for the whole kernel)
    half8 af[2][4][2];   // [i][s(=h)][ks]
    #pragma unroll
    for (int i = 0; i < 2; ++i) {
        const _Float16* ar = A + (size_t)(m0 + wr * 32 + i * 16 + lane16) * 256
                               + quad * 8;
        #pragma unroll
        for (int s = 0; s < 4; ++s)
            #pragma unroll
            for (int ks = 0; ks < 2; ++ks)
                af[i][s][ks] = *(const half8*)(ar + s * 64 + ks * 32);
    }

    // ---- staging geometry (16-KB slice = [128 cols][128 B of k]) ----
    // Wave w stages cols [w*32,w*32+32) as 4 wave-loads of 1 KB (8 cols each).
    // Lane L -> col = colb + (L>>3), phys chunk L&7; fetches LOGICAL chunk
    // (L&7)^(L>>3) (col&7 == L>>3 here), so the XOR'd reader sees B[col][k].
    const int l3 = lane >> 3, l7 = lane & 7;
    const _Float16* pbase = B + (size_t)(wave * 32 + l3) * 256 + (l7 ^ l3) * 8;
    const uint32_t lwave = (uint32_t)wave * 4096;      // byte base in buffer

    // fragment ds_read offsets (bytes within a 16-KB buffer):
    // off(j,ks) = (wc*64+j*16+lane16)*128 + ((ks*4+quad) ^ (lane16&7))*16
    const uint32_t fr_base = (uint32_t)(wc * 64 + lane16) * 128;
    uint32_t cq[2];
    #pragma unroll
    for (int ks = 0; ks < 2; ++ks)
        cq[ks] = (uint32_t)(((ks * 4 + quad) ^ (lane16 & 7)) * 16);

    Top2 t2[2][4];
    #pragma unroll
    for (int i = 0; i < 2; ++i)
        #pragma unroll
        for (int r = 0; r < 4; ++r)
            t2[i][r] = Top2{-3.4e38f, 0x7fffffff, -3.4e38f, 0x7fffffff};

    // stage slice v (v = g*4 + kpart; buffer = kpart = v&3). Wave 0 also
    // stages cnorm[g*128..+256) when v&3==0 (rides the same vmcnt pipe).
    auto STAGE = [&](int v) {
        const _Float16* src = pbase + (size_t)(v >> 2) * 32768 + (v & 3) * 64;
        char* dst = lds + (v & 3) * 16384 + lwave;
        #pragma unroll
        for (int q = 0; q < 4; ++q)
            gll16(src + q * 2048, dst + q * 1024);
        if ((v & 3) == 0 && wave == 0) {
            int g2 = v >> 2;   // g2=63 over-reads 512 B into PART (harmless)
            gll16(cnorm + g2 * 128 + lane * 4, lds + 65536 + (g2 & 1) * 1024);
        }
    };

    // compute slice (g, h) from buffer h: 8 ds_read_b128 + 16 MFMA
    auto COMPUTE = [&](int h, floatx4 (&acc)[2][4]) {
        const char* cur = lds + h * 16384;
        half8 bf[4][2];
        #pragma unroll
        for (int j = 0; j < 4; ++j)
            #pragma unroll
            for (int ks = 0; ks < 2; ++ks)
                bf[j][ks] = *(const half8*)(cur + fr_base + j * 2048 + cq[ks]);
        #pragma unroll
        for (int ks = 0; ks < 2; ++ks)
            #pragma unroll
            for (int i = 0; i < 2; ++i)
                #pragma unroll
                for (int j = 0; j < 4; ++j)
                    acc[i][j] = __builtin_amdgcn_mfma_f32_16x16x32_f16(
                        af[i][h][ks], bf[j][ks], acc[i][j], 0, 0, 0);
    };

    // streaming top-2 update for finished g (registers; C/D: col=lane&15,
    // row=quad*4+reg). Cheap form; exact ties deferred to resolve's fp64.
    auto TOP2 = [&](int g, floatx4 (&acc)[2][4]) {
        const int colb = g * 128 + wc * 64 + lane16;
        #pragma unroll
        for (int i = 0; i < 2; ++i)
            #pragma unroll
            for (int r = 0; r < 4; ++r) {
                Top2& t = t2[i][r];
                #pragma unroll
                for (int j = 0; j < 4; ++j) {
                    float sv = acc[i][j][r];
                    int col = colb + j * 16;
                    bool gt1 = sv > t.s1;
                    bool gt2 = sv > t.s2;
#if __has_builtin(__builtin_amdgcn_fmed3f)
                    float ns2 = __builtin_amdgcn_fmed3f(sv, t.s2, t.s1);
#else
                    float ns2 = gt1 ? t.s1 : (gt2 ? sv : t.s2);
#endif
                    t.i2 = gt1 ? t.i1 : (gt2 ? col : t.i2);
                    t.i1 = gt1 ? col : t.i1;
                    t.s1 = gt1 ? sv  : t.s1;
                    t.s2 = ns2;
                }
            }
    };

    // flush: butterfly + cross-wave merge via topbuf + part write. Raw
    // barriers with lgkmcnt(0) only -- staged loads stay in flight.
    auto FLUSH = [&](int slot) {
        #pragma unroll
        for (int i = 0; i < 2; ++i)
            #pragma unroll
            for (int r = 0; r < 4; ++r) {
                Top2 t = t2[i][r];
                #pragma unroll
                for (int m = 1; m < 16; m <<= 1) {
                    Top2 o;
                    o.s1 = __shfl_xor(t.s1, m); o.i1 = __shfl_xor(t.i1, m);
                    o.s2 = __shfl_xor(t.s2, m); o.i2 = __shfl_xor(t.i2, m);
                    t = merge2(t, o);
                }
                if (lane16 == 0) {
                    int rl = wr * 32 + i * 16 + quad * 4 + r;   // 0..63
                    topbuf[rl * 2 + wc] =
                        make_float4(t.s1, __int_as_float(t.i1),
                                    t.s2, __int_as_float(t.i2));
                }
                t2[i][r] = Top2{-3.4e38f, 0x7fffffff, -3.4e38f, 0x7fffffff};
            }
        asm volatile("s_waitcnt lgkmcnt(0)" ::: "memory");
        __builtin_amdgcn_s_barrier();
        __builtin_amdgcn_sched_barrier(0);
        if (tid < 64) {
            float4 e0 = topbuf[tid * 2 + 0], e1 = topbuf[tid * 2 + 1];
            Top2 a{e0.x, __float_as_int(e0.y), e0.z, __float_as_int(e0.w)};
            Top2 b{e1.x, __float_as_int(e1.y), e1.z, __float_as_int(e1.w)};
            Top2 t = merge2(a, b);
            part[(size_t)(m0 + tid) * 8 + slot] =
                make_float4(t.s1, __int_as_float(t.i1),
                            t.s2, __int_as_float(t.i2));
        }
        asm volatile("s_waitcnt lgkmcnt(0)" ::: "memory");
        __builtin_amdgcn_s_barrier();
        __builtin_amdgcn_sched_barrier(0);
    };

    // prologue: fill 3 pipeline stages; drain only the first (af rides too)
    STAGE(0); STAGE(1); STAGE(2);
    PIPE_SYNC(8);

    for (int g = 0; g < 63; ++g) {
        floatx4 acc[2][4];
        // acc init = -0.5*||c||^2 from the LDS cnorm slot (lgkm, not vmcnt)
        const float* cl = (const float*)(lds + 65536 + (g & 1) * 1024)
                          + wc * 64 + lane16;
        #pragma unroll
        for (int j = 0; j < 4; ++j) {
            float nh = -cl[j * 16];
            acc[0][j] = (floatx4){nh, nh, nh, nh};
            acc[1][j] = acc[0][j];
        }
        const int u0 = g * 4;
        #pragma unroll
        for (int h = 0; h < 4; ++h) {
            STAGE(u0 + h + 3);       // depth-3 prefetch
            COMPUTE(h, acc);
            PIPE_SYNC(8);            // drains only L(u+1)
        }
        TOP2(g, acc);
        if ((g & 7) == 7) FLUSH(g >> 3);
    }
    {   // g = 63 peeled: drain the pipe with descending counted waits
        floatx4 acc[2][4];
        const float* cl = (const float*)(lds + 65536 + 1024) + wc * 64 + lane16;
        #pragma unroll
        for (int j = 0; j < 4; ++j) {
            float nh = -cl[j * 16];
            acc[0][j] = (floatx4){nh, nh, nh, nh};
            acc[1][j] = acc[0][j];
        }
        STAGE(255); COMPUTE(0, acc); PIPE_SYNC(8);
        COMPUTE(1, acc); PIPE_SYNC(4);
        COMPUTE(2, acc); PIPE_SYNC(0);
        COMPUTE(3, acc);
        TOP2(63, acc);
        FLUSH(7);
    }
}

// ---- 4. resolve: merge 8 partials/row, fp64-refine near-ties (R4-proven) ----
__global__ __launch_bounds__(256) void resolve(const float4* __restrict__ part,
                                               const float* __restrict__ gr,
                                               const float* __restrict__ gi,
                                               const float* __restrict__ cb,
                                               int* __restrict__ idx) {
    const int row = blockIdx.x * 256 + threadIdx.x;   // grid 128
    float4 e[8];
    #pragma unroll
    for (int j = 0; j < 8; ++j) e[j] = part[(size_t)row * 8 + j];
    Top2 t{-3.4e38f, 0x7fffffff, -3.4e38f, 0x7fffffff};
    #pragma unroll
    for (int j = 0; j < 8; ++j) {
        Top2 o{e[j].x, __float_as_int(e[j].y), e[j].z, __float_as_int(e[j].w)};
        t = merge2(t, o);
    }
    int best = t.i1;
    const float MARGIN = 0.12f;   // ~7.7 sigma of f16-screen score-diff noise
    if (t.s1 - t.s2 < MARGIN) {
        double bd = 1e300; int bi = 0x7fffffff;
        float cut = t.s1 - MARGIN;
        const float* zr = gr + (size_t)row * 128;
        const float* zi = gi + (size_t)row * 128;
        #pragma unroll
        for (int j = 0; j < 8; ++j) {
            #pragma unroll
            for (int c = 0; c < 2; ++c) {
                float sv = c ? e[j].z : e[j].x;
                int   ci = __float_as_int(c ? e[j].w : e[j].y);
                if (sv >= cut && (unsigned)ci < 8192u) {   // clamp: no wild reads
                    const float* crow = cb + (size_t)ci * 256;
                    double d = 0.0;
                    for (int k = 0; k < 128; ++k) {
                        double a = (double)zr[k] - (double)crow[k];
                        double b = (double)zi[k] - (double)crow[128 + k];
                        d += a * a + b * b;
                    }
                    if (d < bd || (d == bd && ci < bi)) { bd = d; bi = ci; }
                }
            }
        }
        if ((unsigned)bi < 8192u) best = bi;
    }
    idx[row] = ((unsigned)best < 8192u) ? best : 0;
}

// ---- 5a. zero the vq accumulator ----
__global__ void zero_vq(float* __restrict__ out, size_t vq_off) {
    out[vq_off] = 0.f;
}

// ---- 5b. gather + proposal(REAL part only) + salience + vq (one wave/row) ----
__global__ __launch_bounds__(256) void gather_epi(const int* __restrict__ idx,
                                                  const float* __restrict__ gr,
                                                  const float* __restrict__ gi,
                                                  const float* __restrict__ cb,
                                                  const float* __restrict__ salw,
                                                  const float* __restrict__ salb,
                                                  float* __restrict__ out,
                                                  size_t sal_off, size_t vq_off) {
    const int wave = threadIdx.x >> 6, lane = threadIdx.x & 63;
    const int row = blockIdx.x * 4 + wave;
    int id = idx[row];
    if ((unsigned)id >= 8192u) id = 0;   // clamp: no wild reads

    float4 c4 = ((const float4*)(cb + (size_t)id * 256))[lane];
    float4 z4 = (lane < 32) ? ((const float4*)(gr + (size_t)row * 128))[lane]
                            : ((const float4*)(gi + (size_t)row * 128))[lane - 32];

    float dx = c4.x - z4.x, dy = c4.y - z4.y, dz = c4.z - z4.z, dw = c4.w - z4.w;
    float vq = dx * dx + dy * dy + dz * dz + dw * dw;
    float4 w4 = ((const float4*)salw)[lane];
    float sal = c4.x * w4.x + c4.y * w4.y + c4.z * w4.z + c4.w * w4.w;
    #pragma unroll
    for (int m = 1; m < 64; m <<= 1) {
        vq  += __shfl_xor(vq, m);
        sal += __shfl_xor(sal, m);
    }

    // proposal: real part only — lanes 0..31 hold c[0..128) as float4s
    if (lane < 32 && (size_t)(row + 1) * 128 <= sal_off) {
        float4* op = (float4*)(out + (size_t)row * 128);
        op[lane] = c4;
    }
    if (lane == 0 && sal_off + row < vq_off)
        out[sal_off + row] = sal + salb[0];

    __shared__ float vqs[4];
    if (lane == 0) vqs[wave] = vq;
    __syncthreads();
    if (threadIdx.x == 0) {
        float p = (vqs[0] + vqs[1] + vqs[2] + vqs[3]) * (1.25f / 8388608.f);
        atomicAdd(out + vq_off, p);
    }
}

extern "C" void kernel_launch(void* const* d_in, const int* in_sizes, int n_in,
                              void* d_out, int out_size, void* d_ws, size_t ws_size,
                              hipStream_t stream) {
    const float* gr = (const float*)d_in[0];   // gw_real  [8,4096,128]
    const float* gi = (const float*)d_in[1];   // gw_imag  [8,4096,128]
    const float* cb = (const float*)d_in[2];   // codebook [8192,256]
    const float* sw = (const float*)d_in[3];   // sal_w    [1,256]
    const float* sb = (const float*)d_in[4];   // sal_b    [1]
    float* out = (float*)d_out;

    // Output offsets (out_size = 4,227,073 floats:
    // proposal-real 4,194,304 | salience 32,768 | vq_loss 1).
    size_t vq_off  = (size_t)out_size - 1;
    size_t sal_off = (size_t)out_size - 1 - 32768;

    char* base = (char*)d_ws;
    int*  idxb = (int*)(base + IDX_OFF);
    _Float16* A    = (_Float16*)(base + A_OFF);
    _Float16* Bq   = (_Float16*)(base + B_OFF);
    float*    cn   = (float*)   (base + CN_OFF);
    float4*   part = (float4*)  (base + PART_OFF);

    prep_z<<<8192, 256, 0, stream>>>(gr, gi, A);
    prep_c<<<8192, 64, 0, stream>>>(cb, Bq, cn);
    gemm_argmin<<<512, 256, 0, stream>>>(A, Bq, cn, part);
    resolve<<<128, 256, 0, stream>>>(part, gr, gi, cb, idxb);
    zero_vq<<<1, 1, 0, stream>>>(out, vq_off);
    gather_epi<<<8192, 256, 0, stream>>>(idxb, gr, gi, cb, sw, sb, out,
                                         sal_off, vq_off);
}